// Round 3
// baseline (397.807 us; speedup 1.0000x reference)
//
#include <hip/hip_runtime.h>

#define DCONST 128   // embedding dim
#define CCTX   8     // context size
#define CK     40    // C*K negative rows per example

// stable log-sigmoid: log_sigmoid(x) = min(x,0) - log1p(exp(-|x|))
__device__ __forceinline__ float logsig(float x) {
    float ax = fabsf(x);
    return fminf(x, 0.0f) - log1pf(__expf(-ax));
}

__global__ __launch_bounds__(256) void cbow_loss_kernel(
    const float* __restrict__ uw,      // [VOCAB,128]
    const float* __restrict__ vw,      // [VOCAB,128]
    const int*   __restrict__ pos_u,   // [B*C]
    const int*   __restrict__ pos_v,   // [B*C]
    const int*   __restrict__ neg_v,   // [B*C*K] = [B,40] row indices
    float*       __restrict__ out,     // scalar
    int B, float invB)
{
    const int lane = threadIdx.x & 63;
    const int t    = lane & 15;        // 16 lanes cover d=0..127, 8 floats each
    const int g    = lane >> 4;        // 4 groups -> 4 neg rows in parallel
    const int wid    = (blockIdx.x * blockDim.x + threadIdx.x) >> 6;
    const int nwaves = (gridDim.x * blockDim.x) >> 6;

    float acc = 0.0f;

    for (int b = wid; b < B; b += nwaves) {
        const int base = b * CCTX;

        // ---- V = sum of 8 context rows (this lane's 8 elements) ----
        float4 Va = make_float4(0.f, 0.f, 0.f, 0.f);
        float4 Vb = make_float4(0.f, 0.f, 0.f, 0.f);
        #pragma unroll
        for (int c = 0; c < CCTX; ++c) {
            const int row = pos_v[base + c];
            const float4* p = (const float4*)(vw + (size_t)row * DCONST + t * 8);
            float4 a = p[0], b2 = p[1];
            Va.x += a.x;  Va.y += a.y;  Va.z += a.z;  Va.w += a.w;
            Vb.x += b2.x; Vb.y += b2.y; Vb.z += b2.z; Vb.w += b2.w;
        }

        // ---- positive score: dot(U_row, V) ----
        const int urow = pos_u[base];
        const float4* up = (const float4*)(uw + (size_t)urow * DCONST + t * 8);
        float4 ua = up[0], ub = up[1];
        float p = ua.x * Va.x + ua.y * Va.y + ua.z * Va.z + ua.w * Va.w
                + ub.x * Vb.x + ub.y * Vb.y + ub.z * Vb.z + ub.w * Vb.w;
        p += __shfl_xor(p, 1);
        p += __shfl_xor(p, 2);
        p += __shfl_xor(p, 4);
        p += __shfl_xor(p, 8);
        float pos_score = fminf(fmaxf(p, -10.0f), 10.0f);
        float loss = -logsig(pos_score);

        // ---- 40 negative scores, 4 at a time (one per 16-lane group) ----
        float negacc = 0.0f;
        const long long nb = (long long)b * CK;
        #pragma unroll
        for (int it = 0; it < CK / 4; ++it) {
            const int row = neg_v[nb + it * 4 + g];
            const float4* q = (const float4*)(vw + (size_t)row * DCONST + t * 8);
            float4 ra = q[0], rb = q[1];
            float s = ra.x * Va.x + ra.y * Va.y + ra.z * Va.z + ra.w * Va.w
                    + rb.x * Vb.x + rb.y * Vb.y + rb.z * Vb.z + rb.w * Vb.w;
            s += __shfl_xor(s, 1);
            s += __shfl_xor(s, 2);
            s += __shfl_xor(s, 4);
            s += __shfl_xor(s, 8);
            s = fminf(fmaxf(s, -10.0f), 10.0f);
            negacc += -logsig(-s);
        }
        // each group's negacc covers its 10 rows; sum the 4 groups
        negacc += __shfl_xor(negacc, 16);
        negacc += __shfl_xor(negacc, 32);

        loss += negacc * (1.0f / CK);
        acc  += loss;
    }

    // all lanes hold identical per-wave totals after the butterflies
    if (lane == 0) atomicAdd(out, acc * invB);
}

extern "C" void kernel_launch(void* const* d_in, const int* in_sizes, int n_in,
                              void* d_out, int out_size, void* d_ws, size_t ws_size,
                              hipStream_t stream) {
    const float* uw    = (const float*)d_in[0];
    const float* vw    = (const float*)d_in[1];
    const int*   pos_u = (const int*)d_in[2];
    const int*   pos_v = (const int*)d_in[3];
    const int*   neg_v = (const int*)d_in[4];
    float* out = (float*)d_out;

    const int B = in_sizes[2] / CCTX;   // 32768

    // d_out is poisoned with 0xAA before every launch — zero it (capture-safe)
    hipMemsetAsync(out, 0, sizeof(float), stream);

    dim3 block(256);                    // 4 waves/block
    dim3 grid(2048);                    // 8192 waves, grid-stride over B
    cbow_loss_kernel<<<grid, block, 0, stream>>>(uw, vw, pos_u, pos_v, neg_v,
                                                 out, B, 1.0f / (float)B);
}

// Round 6
// 388.972 us; speedup vs baseline: 1.0227x; 1.0227x over previous
//
#include <hip/hip_runtime.h>

#define DCONST 128   // embedding dim
#define CCTX   8     // context size
#define CK     40    // C*K negative rows per example

typedef __attribute__((ext_vector_type(8))) unsigned short us8;
typedef __attribute__((ext_vector_type(4))) float f32x4;

// stable log-sigmoid: log_sigmoid(x) = min(x,0) - log1p(exp(-|x|))
__device__ __forceinline__ float logsig(float x) {
    float ax = fabsf(x);
    return fminf(x, 0.0f) - log1pf(__expf(-ax));
}

__device__ __forceinline__ unsigned short f32_to_bf16_rne(float f) {
    unsigned int u = __float_as_uint(f);
    u += 0x7fffu + ((u >> 16) & 1u);          // round-to-nearest-even
    return (unsigned short)(u >> 16);
}
__device__ __forceinline__ float bf16_to_f32(unsigned short h) {
    return __uint_as_float(((unsigned int)h) << 16);
}

// ---- pass 1: vw f32 -> bf16 into d_ws (51.2 MB, L3-resident) ----
// nontemporal loads keep the once-read 102 MB f32 stream from evicting
// the bf16 table we're writing.
__global__ __launch_bounds__(256) void convert_vw_kernel(
    const float* __restrict__ vw, unsigned short* __restrict__ vwb, int n8)
{
    int idx    = blockIdx.x * blockDim.x + threadIdx.x;
    int stride = gridDim.x * blockDim.x;
    for (int i = idx; i < n8; i += stride) {
        const f32x4* p = (const f32x4*)(vw + (size_t)i * 8);
        f32x4 a = __builtin_nontemporal_load(p);
        f32x4 b = __builtin_nontemporal_load(p + 1);
        us8 o;
        o[0] = f32_to_bf16_rne(a.x); o[1] = f32_to_bf16_rne(a.y);
        o[2] = f32_to_bf16_rne(a.z); o[3] = f32_to_bf16_rne(a.w);
        o[4] = f32_to_bf16_rne(b.x); o[5] = f32_to_bf16_rne(b.y);
        o[6] = f32_to_bf16_rne(b.z); o[7] = f32_to_bf16_rne(b.w);
        *(us8*)(vwb + (size_t)i * 8) = o;
    }
}

// ---- pass 2: gather from bf16 vw (256 B rows, one us8 load/lane) ----
__global__ __launch_bounds__(256) void cbow_loss_bf16_kernel(
    const float*          __restrict__ uw,     // [VOCAB,128] f32
    const unsigned short* __restrict__ vwb,    // [VOCAB,128] bf16
    const int*            __restrict__ pos_u,
    const int*            __restrict__ pos_v,
    const int*            __restrict__ neg_v,
    float*                __restrict__ out,
    int B, float invB)
{
    const int lane = threadIdx.x & 63;
    const int t    = lane & 15;        // 16 lanes cover d=0..127, 8 elems each
    const int g    = lane >> 4;        // 4 groups -> 4 neg rows in parallel
    const int wid    = (blockIdx.x * blockDim.x + threadIdx.x) >> 6;
    const int nwaves = (gridDim.x * blockDim.x) >> 6;

    float acc = 0.0f;

    for (int b = wid; b < B; b += nwaves) {
        const int base = b * CCTX;

        // ---- V = sum of 8 context rows (this lane's 8 elements) ----
        float V0=0,V1=0,V2=0,V3=0,V4=0,V5=0,V6=0,V7=0;
        #pragma unroll
        for (int c = 0; c < CCTX; ++c) {
            const int row = pos_v[base + c];
            us8 r = *(const us8*)(vwb + (size_t)row * DCONST + t * 8);
            V0 += bf16_to_f32(r[0]); V1 += bf16_to_f32(r[1]);
            V2 += bf16_to_f32(r[2]); V3 += bf16_to_f32(r[3]);
            V4 += bf16_to_f32(r[4]); V5 += bf16_to_f32(r[5]);
            V6 += bf16_to_f32(r[6]); V7 += bf16_to_f32(r[7]);
        }

        // ---- positive score: dot(U_row, V); u-row used once -> nt load ----
        const int urow = pos_u[base];
        const f32x4* up = (const f32x4*)(uw + (size_t)urow * DCONST + t * 8);
        f32x4 ua = __builtin_nontemporal_load(up);
        f32x4 ub = __builtin_nontemporal_load(up + 1);
        float p = ua.x*V0 + ua.y*V1 + ua.z*V2 + ua.w*V3
                + ub.x*V4 + ub.y*V5 + ub.z*V6 + ub.w*V7;
        p += __shfl_xor(p, 1);
        p += __shfl_xor(p, 2);
        p += __shfl_xor(p, 4);
        p += __shfl_xor(p, 8);
        float pos_score = fminf(fmaxf(p, -10.0f), 10.0f);
        float loss = -logsig(pos_score);

        // ---- 40 negative scores, 4 at a time (one per 16-lane group) ----
        float negacc = 0.0f;
        const long long nb = (long long)b * CK;
        #pragma unroll
        for (int it = 0; it < CK / 4; ++it) {
            const int row = neg_v[nb + it * 4 + g];
            us8 r = *(const us8*)(vwb + (size_t)row * DCONST + t * 8);
            float s = bf16_to_f32(r[0])*V0 + bf16_to_f32(r[1])*V1
                    + bf16_to_f32(r[2])*V2 + bf16_to_f32(r[3])*V3
                    + bf16_to_f32(r[4])*V4 + bf16_to_f32(r[5])*V5
                    + bf16_to_f32(r[6])*V6 + bf16_to_f32(r[7])*V7;
            s += __shfl_xor(s, 1);
            s += __shfl_xor(s, 2);
            s += __shfl_xor(s, 4);
            s += __shfl_xor(s, 8);
            s = fminf(fmaxf(s, -10.0f), 10.0f);
            negacc += -logsig(-s);
        }
        negacc += __shfl_xor(negacc, 16);
        negacc += __shfl_xor(negacc, 32);

        loss += negacc * (1.0f / CK);
        acc  += loss;
    }

    if (lane == 0) atomicAdd(out, acc * invB);
}

// ---- fallback: direct f32 gather (if ws too small for bf16 table) ----
__global__ __launch_bounds__(256) void cbow_loss_f32_kernel(
    const float* __restrict__ uw, const float* __restrict__ vw,
    const int* __restrict__ pos_u, const int* __restrict__ pos_v,
    const int* __restrict__ neg_v, float* __restrict__ out,
    int B, float invB)
{
    const int lane = threadIdx.x & 63;
    const int t    = lane & 15;
    const int g    = lane >> 4;
    const int wid    = (blockIdx.x * blockDim.x + threadIdx.x) >> 6;
    const int nwaves = (gridDim.x * blockDim.x) >> 6;
    float acc = 0.0f;
    for (int b = wid; b < B; b += nwaves) {
        const int base = b * CCTX;
        float4 Va = make_float4(0.f,0.f,0.f,0.f), Vb = make_float4(0.f,0.f,0.f,0.f);
        #pragma unroll
        for (int c = 0; c < CCTX; ++c) {
            const int row = pos_v[base + c];
            const float4* p = (const float4*)(vw + (size_t)row * DCONST + t * 8);
            float4 a = p[0], b2 = p[1];
            Va.x+=a.x; Va.y+=a.y; Va.z+=a.z; Va.w+=a.w;
            Vb.x+=b2.x; Vb.y+=b2.y; Vb.z+=b2.z; Vb.w+=b2.w;
        }
        const int urow = pos_u[base];
        const float4* up = (const float4*)(uw + (size_t)urow * DCONST + t * 8);
        float4 ua = up[0], ub = up[1];
        float p = ua.x*Va.x + ua.y*Va.y + ua.z*Va.z + ua.w*Va.w
                + ub.x*Vb.x + ub.y*Vb.y + ub.z*Vb.z + ub.w*Vb.w;
        p += __shfl_xor(p, 1); p += __shfl_xor(p, 2);
        p += __shfl_xor(p, 4); p += __shfl_xor(p, 8);
        float loss = -logsig(fminf(fmaxf(p, -10.0f), 10.0f));
        float negacc = 0.0f;
        const long long nb = (long long)b * CK;
        #pragma unroll
        for (int it = 0; it < CK / 4; ++it) {
            const int row = neg_v[nb + it * 4 + g];
            const float4* q = (const float4*)(vw + (size_t)row * DCONST + t * 8);
            float4 ra = q[0], rb = q[1];
            float s = ra.x*Va.x + ra.y*Va.y + ra.z*Va.z + ra.w*Va.w
                    + rb.x*Vb.x + rb.y*Vb.y + rb.z*Vb.z + rb.w*Vb.w;
            s += __shfl_xor(s, 1); s += __shfl_xor(s, 2);
            s += __shfl_xor(s, 4); s += __shfl_xor(s, 8);
            negacc += -logsig(-fminf(fmaxf(s, -10.0f), 10.0f));
        }
        negacc += __shfl_xor(negacc, 16);
        negacc += __shfl_xor(negacc, 32);
        acc += loss + negacc * (1.0f / CK);
    }
    if (lane == 0) atomicAdd(out, acc * invB);
}

extern "C" void kernel_launch(void* const* d_in, const int* in_sizes, int n_in,
                              void* d_out, int out_size, void* d_ws, size_t ws_size,
                              hipStream_t stream) {
    const float* uw    = (const float*)d_in[0];
    const float* vw    = (const float*)d_in[1];
    const int*   pos_u = (const int*)d_in[2];
    const int*   pos_v = (const int*)d_in[3];
    const int*   neg_v = (const int*)d_in[4];
    float* out = (float*)d_out;

    const int B = in_sizes[2] / CCTX;                 // 32768
    const size_t vw_elems = (size_t)in_sizes[1];      // VOCAB*128
    const size_t need     = vw_elems * 2;             // bf16 table bytes

    (void)hipMemsetAsync(out, 0, sizeof(float), stream);  // d_out is 0xAA-poisoned

    dim3 block(256);
    dim3 grid(2048);                                  // 8192 waves

    if (ws_size >= need) {
        unsigned short* vwb = (unsigned short*)d_ws;
        convert_vw_kernel<<<grid, block, 0, stream>>>(vw, vwb, (int)(vw_elems / 8));
        cbow_loss_bf16_kernel<<<grid, block, 0, stream>>>(uw, vwb, pos_u, pos_v,
                                                          neg_v, out, B, 1.0f / (float)B);
    } else {
        cbow_loss_f32_kernel<<<grid, block, 0, stream>>>(uw, vw, pos_u, pos_v,
                                                         neg_v, out, B, 1.0f / (float)B);
    }
}